// Round 1
// baseline (83180.835 us; speedup 1.0000x reference)
//
#include <hip/hip_runtime.h>
#include <hip/hip_bf16.h>
#include <cstdint>
#include <cstddef>

#define SEQ 4096
#define HID 1024
#define G4  4096
#define NWG 64
#define TPB 512
#define UPL 64

// ---------------- persistent device scratch (avoids ws_size unknowns) ----------
__device__ float    g_xg[(size_t)SEQ * G4];   // 64 MB: input-gate preactivations
__device__ float    g_y [(size_t)SEQ * HID];  // 16 MB: bottom LSTM outputs
__device__ float    g_h [2][HID];             // double-buffered bottom h
__device__ float    g_h2[2][HID];             // double-buffered top h
__device__ float    g_bias2[HID];             // hw_b + cw_b + att_bias + ctx@cw_w.T
__device__ float    g_e[SEQ];
__device__ float    g_p[SEQ];
__device__ float    g_invden[SEQ];
__device__ float    g_csum[64 * HID];
__device__ unsigned g_bar;

__global__ void k_init() { g_bar = 0u; }

// ---------------- K1: xg = x @ bot_Wih^T + (bih + bhh), fp32 tiled GEMM --------
#define BMT 128
#define BNT 128
#define BKT 32

__global__ __launch_bounds__(256) void k_gemm_xg(const float* __restrict__ A,
                                                 const float* __restrict__ B,
                                                 const float* __restrict__ bias0,
                                                 const float* __restrict__ bias1)
{
  __shared__ float As[BKT][BMT + 4];
  __shared__ float Bs[BKT][BNT + 4];
  const int t  = threadIdx.x;
  const int bn = blockIdx.x;
  const int bm = blockIdx.y;
  const int m0 = (t & 15) * 8;
  const int n0 = (t >> 4) * 8;

  float acc[8][8];
#pragma unroll
  for (int i = 0; i < 8; i++)
#pragma unroll
    for (int j = 0; j < 8; j++) acc[i][j] = 0.f;

  for (int k0 = 0; k0 < 1024; k0 += BKT) {
#pragma unroll
    for (int i = 0; i < 4; i++) {
      const int idx = i * 256 + t;        // 0..1023
      const int m   = idx >> 3;           // 0..127
      const int k4  = (idx & 7) << 2;     // 0..28
      const float4 av = *(const float4*)&A[(size_t)(bm * BMT + m) * 1024 + k0 + k4];
      As[k4 + 0][m] = av.x; As[k4 + 1][m] = av.y; As[k4 + 2][m] = av.z; As[k4 + 3][m] = av.w;
      const float4 bv = *(const float4*)&B[(size_t)(bn * BNT + m) * 1024 + k0 + k4];
      Bs[k4 + 0][m] = bv.x; Bs[k4 + 1][m] = bv.y; Bs[k4 + 2][m] = bv.z; Bs[k4 + 3][m] = bv.w;
    }
    __syncthreads();
#pragma unroll
    for (int k = 0; k < BKT; k++) {
      float a[8], b[8];
      *(float4*)&a[0] = *(const float4*)&As[k][m0];
      *(float4*)&a[4] = *(const float4*)&As[k][m0 + 4];
      *(float4*)&b[0] = *(const float4*)&Bs[k][n0];
      *(float4*)&b[4] = *(const float4*)&Bs[k][n0 + 4];
#pragma unroll
      for (int i = 0; i < 8; i++)
#pragma unroll
        for (int j = 0; j < 8; j++) acc[i][j] = fmaf(a[i], b[j], acc[i][j]);
    }
    __syncthreads();
  }

  float bb[8];
#pragma unroll
  for (int j = 0; j < 8; j++) {
    const int gc = bn * BNT + n0 + j;
    bb[j] = bias0[gc] + bias1[gc];
  }
#pragma unroll
  for (int i = 0; i < 8; i++) {
    const size_t off = (size_t)(bm * BMT + m0 + i) * G4 + bn * BNT + n0;
    float4 v0, v1;
    v0.x = acc[i][0] + bb[0]; v0.y = acc[i][1] + bb[1]; v0.z = acc[i][2] + bb[2]; v0.w = acc[i][3] + bb[3];
    v1.x = acc[i][4] + bb[4]; v1.y = acc[i][5] + bb[5]; v1.z = acc[i][6] + bb[6]; v1.w = acc[i][7] + bb[7];
    *(float4*)&g_xg[off]     = v0;
    *(float4*)&g_xg[off + 4] = v1;
  }
}

// ---------------- K2: persistent LSTM kernel with device-scope grid barrier ----
__device__ __forceinline__ void grid_sync(unsigned target)
{
  __threadfence();              // release: make h/y writes device-visible (wbL2)
  __syncthreads();
  if (threadIdx.x == 0) {
    __hip_atomic_fetch_add(&g_bar, 1u, __ATOMIC_RELEASE, __HIP_MEMORY_SCOPE_AGENT);
    while (__hip_atomic_load(&g_bar, __ATOMIC_RELAXED, __HIP_MEMORY_SCOPE_AGENT) < target) { }
  }
  __syncthreads();
  __threadfence();              // acquire: invalidate L1/L2 before reading remote h
}

__device__ __forceinline__ float seg_dot32(const float4* __restrict__ wv,
                                           const float* __restrict__ hb, int seg)
{
  float acc = 0.f;
#pragma unroll
  for (int k = 0; k < 32; k++) {
    const float4 hv = *(const float4*)&hb[((k + seg) & 31) << 2]; // rotated: bank-conflict-free
    acc = fmaf(wv[k].x, hv.x, acc);
    acc = fmaf(wv[k].y, hv.y, acc);
    acc = fmaf(wv[k].z, hv.z, acc);
    acc = fmaf(wv[k].w, hv.w, acc);
  }
  return acc;
}

__device__ __forceinline__ void load_wrow(float4* __restrict__ wv,
                                          const float* __restrict__ W, int row, int seg)
{
  const float* wr = W + (size_t)row * HID + (seg << 7);
#pragma unroll
  for (int k = 0; k < 32; k++) wv[k] = *(const float4*)&wr[((k + seg) & 31) << 2];
}

__global__ __launch_bounds__(TPB, 2) void k_lstm(
    const float* __restrict__ bot_Whh,
    const float* __restrict__ top_Wih, const float* __restrict__ top_Whh,
    const float* __restrict__ top_bih, const float* __restrict__ top_bhh,
    const float* __restrict__ hw_b,    const float* __restrict__ cw_w,
    const float* __restrict__ cw_b,    const float* __restrict__ att_bias)
{
  const int w = blockIdx.x;              // 0..63, owns hidden units [16w,16w+16)
  const int t = threadIdx.x;
  const int r_local = t >> 3;            // 0..63 (gate*16 + hu_local)
  const int seg     = t & 7;             // 0..7, 128-wide column segment
  const int row = ((r_local >> 4) << 10) + (w << 4) + (r_local & 15); // gate*1024 + hu

  __shared__ float h_lds[HID];
  __shared__ float gates_lds[64];
  __shared__ float xg2_lds[UPL][64];

  float4 wv[32];                         // 128 fp32 weights, register-resident
  load_wrow(wv, bot_Whh, row, seg);

  float c_state = 0.f;
  unsigned gen = 0;

  // ---- bottom LSTM: 4096 sequential steps ----
  for (int step = 0; step < SEQ; step++) {
    float xval = 0.f;
    if (seg == 0) xval = g_xg[(size_t)step * G4 + row];   // issued early
    if (step == 0) {
      for (int i = t; i < HID; i += TPB) h_lds[i] = 0.f;
    } else if (t < 256) {
      *(float4*)&h_lds[t << 2] = *(const float4*)&g_h[(step + 1) & 1][t << 2];
    }
    __syncthreads();
    float acc = seg_dot32(wv, &h_lds[seg << 7], seg);
    acc += __shfl_xor(acc, 4);
    acc += __shfl_xor(acc, 2);
    acc += __shfl_xor(acc, 1);
    if (seg == 0) gates_lds[r_local] = acc + xval;
    __syncthreads();
    if (t < 16) {
      const float gi = gates_lds[t];
      const float gf = gates_lds[16 + t];
      const float gg = gates_lds[32 + t];
      const float go = gates_lds[48 + t];
      const float ii = 1.f / (1.f + expf(-gi));
      const float ff = 1.f / (1.f + expf(-gf));
      c_state = ff * c_state + ii * tanhf(gg);
      const float hh = (1.f / (1.f + expf(-go))) * tanhf(c_state);
      g_h[step & 1][(w << 4) + t] = hh;            // double-buffered publish
      g_y[(size_t)step * HID + (w << 4) + t] = hh;
    }
    ++gen;
    grid_sync(gen * NWG);
  }

  // ---- top-LSTM input projection: xg2[s] = y[64s+63] @ top_Wih^T + bias ----
  load_wrow(wv, top_Wih, row, seg);
  const float tb = top_bih[row] + top_bhh[row];
  for (int s = 0; s < UPL; s++) {
    __syncthreads();
    if (t < 256)
      *(float4*)&h_lds[t << 2] = *(const float4*)&g_y[(size_t)(64 * s + 63) * HID + (t << 2)];
    __syncthreads();
    float acc = seg_dot32(wv, &h_lds[seg << 7], seg);
    acc += __shfl_xor(acc, 4);
    acc += __shfl_xor(acc, 2);
    acc += __shfl_xor(acc, 1);
    if (seg == 0) xg2_lds[s][r_local] = acc + tb;
  }

  // ---- top recurrence: 64 steps ----
  load_wrow(wv, top_Whh, row, seg);
  c_state = 0.f;
  for (int s = 0; s < UPL; s++) {
    if (s == 0) {
      __syncthreads();
      for (int i = t; i < HID; i += TPB) h_lds[i] = 0.f;
    } else if (t < 256) {
      *(float4*)&h_lds[t << 2] = *(const float4*)&g_h2[(s + 1) & 1][t << 2];
    }
    __syncthreads();
    float acc = seg_dot32(wv, &h_lds[seg << 7], seg);
    acc += __shfl_xor(acc, 4);
    acc += __shfl_xor(acc, 2);
    acc += __shfl_xor(acc, 1);
    if (seg == 0) gates_lds[r_local] = acc + xg2_lds[s][r_local];
    __syncthreads();
    if (t < 16) {
      const float gi = gates_lds[t];
      const float gf = gates_lds[16 + t];
      const float gg = gates_lds[32 + t];
      const float go = gates_lds[48 + t];
      const float ii = 1.f / (1.f + expf(-gi));
      const float ff = 1.f / (1.f + expf(-gf));
      c_state = ff * c_state + ii * tanhf(gg);
      const float hh = (1.f / (1.f + expf(-go))) * tanhf(c_state);
      g_h2[s & 1][(w << 4) + t] = hh;
    }
    ++gen;
    grid_sync(gen * NWG);
  }

  // ---- bias2[j] = hw_b + cw_b + att_bias + ctx @ cw_w^T (ctx = g_h2[1]) ----
  __syncthreads();
  if (t < 256) *(float4*)&h_lds[t << 2] = *(const float4*)&g_h2[1][t << 2];
  __syncthreads();
  {
    const int jl = t >> 5;            // 0..15
    const int ks = t & 31;            // 0..31
    const int j  = (w << 4) + jl;
    const float* cr = cw_w + (size_t)j * HID + (ks << 5);
    const float* hr = &h_lds[ks << 5];
    float a2 = 0.f;
#pragma unroll
    for (int k = 0; k < 32; k++) a2 = fmaf(cr[k], hr[k], a2);
    a2 += __shfl_xor(a2, 16);
    a2 += __shfl_xor(a2, 8);
    a2 += __shfl_xor(a2, 4);
    a2 += __shfl_xor(a2, 2);
    a2 += __shfl_xor(a2, 1);
    if (ks == 0) g_bias2[j] = a2 + hw_b[j] + cw_b[j] + att_bias[j];
  }
}

// ---------------- K3: e[t] = sum_j v2s_w[j]*tanh(y_t . hw_w[j] + bias2[j]) ----
__global__ __launch_bounds__(256) void k_attn_e(const float* __restrict__ hw_w,
                                                const float* __restrict__ v2s_w,
                                                const float* __restrict__ v2s_b)
{
  __shared__ float ys[16][1028];
  __shared__ float ws[16][1028];
  const int b  = blockIdx.x;          // row block: rows [16b,16b+16)
  const int t  = threadIdx.x;
  const int rg = t >> 6;              // 0..3 (row group of 4)
  const int fg = (t >> 4) & 3;        // 0..3 (feature group of 4)
  const int ks = t & 15;              // 0..15 (k segment of 64)

#pragma unroll
  for (int i = 0; i < 16; i++) {
    const int idx = i * 256 + t;
    const int r   = idx >> 8;
    const int c4  = (idx & 255) << 2;
    *(float4*)&ys[r][c4] = *(const float4*)&g_y[(size_t)((b << 4) + r) * HID + c4];
  }

  float e_acc[4] = {0.f, 0.f, 0.f, 0.f};
  for (int f0 = 0; f0 < HID; f0 += 16) {
    __syncthreads();
#pragma unroll
    for (int i = 0; i < 16; i++) {
      const int idx = i * 256 + t;
      const int r   = idx >> 8;
      const int c4  = (idx & 255) << 2;
      *(float4*)&ws[r][c4] = *(const float4*)&hw_w[(size_t)(f0 + r) * HID + c4];
    }
    __syncthreads();

    float acc[4][4];
#pragma unroll
    for (int u = 0; u < 4; u++)
#pragma unroll
      for (int v = 0; v < 4; v++) acc[u][v] = 0.f;

#pragma unroll
    for (int m = 0; m < 16; m++) {
      const int k4 = (ks << 6) + (((m + ks) & 15) << 2);  // rotated k within segment
      float4 av[4], bv[4];
#pragma unroll
      for (int u = 0; u < 4; u++) av[u] = *(const float4*)&ys[(rg << 2) + u][k4];
#pragma unroll
      for (int v = 0; v < 4; v++) bv[v] = *(const float4*)&ws[(fg << 2) + v][k4];
#pragma unroll
      for (int u = 0; u < 4; u++)
#pragma unroll
        for (int v = 0; v < 4; v++) {
          acc[u][v] = fmaf(av[u].x, bv[v].x, acc[u][v]);
          acc[u][v] = fmaf(av[u].y, bv[v].y, acc[u][v]);
          acc[u][v] = fmaf(av[u].z, bv[v].z, acc[u][v]);
          acc[u][v] = fmaf(av[u].w, bv[v].w, acc[u][v]);
        }
    }
#pragma unroll
    for (int u = 0; u < 4; u++)
#pragma unroll
      for (int v = 0; v < 4; v++) {
        float s2 = acc[u][v];
        s2 += __shfl_xor(s2, 8);
        s2 += __shfl_xor(s2, 4);
        s2 += __shfl_xor(s2, 2);
        s2 += __shfl_xor(s2, 1);
        acc[u][v] = s2;
      }
    if (ks == 0) {
#pragma unroll
      for (int v = 0; v < 4; v++) {
        const int j = f0 + (fg << 2) + v;
        const float bias = g_bias2[j];
        const float vw   = v2s_w[j];
#pragma unroll
        for (int u = 0; u < 4; u++)
          e_acc[u] += vw * tanhf(acc[u][v] + bias);
      }
    }
  }
#pragma unroll
  for (int u = 0; u < 4; u++) {
    float s2 = e_acc[u];
    s2 += __shfl_xor(s2, 16);
    s2 += __shfl_xor(s2, 32);
    if (fg == 0 && ks == 0) g_e[(b << 4) + (rg << 2) + u] = s2 + v2s_b[0];
  }
}

// ---------------- K4a: p = exp(e - max e); invden = 1/cumsum(p) --------------
__global__ __launch_bounds__(1024) void k_softmax()
{
  const int t  = threadIdx.x;
  const int ln = t & 63;
  const int wv = t >> 6;
  __shared__ float sred[16];
  __shared__ float soff[16];
  __shared__ float sM;

  const float4 ev = *(const float4*)&g_e[t << 2];
  float mx = fmaxf(fmaxf(ev.x, ev.y), fmaxf(ev.z, ev.w));
#pragma unroll
  for (int d = 32; d >= 1; d >>= 1) mx = fmaxf(mx, __shfl_xor(mx, d));
  if (ln == 0) sred[wv] = mx;
  __syncthreads();
  if (t == 0) {
    float m2 = sred[0];
    for (int i = 1; i < 16; i++) m2 = fmaxf(m2, sred[i]);
    sM = m2;
  }
  __syncthreads();
  const float M = sM;
  float4 pv;
  pv.x = expf(ev.x - M); pv.y = expf(ev.y - M); pv.z = expf(ev.z - M); pv.w = expf(ev.w - M);
  *(float4*)&g_p[t << 2] = pv;

  const float s = pv.x + pv.y + pv.z + pv.w;
  float ps = s;
#pragma unroll
  for (int d = 1; d < 64; d <<= 1) {
    const float v = __shfl_up(ps, d);
    if (ln >= d) ps += v;
  }
  __syncthreads();
  if (ln == 63) sred[wv] = ps;
  __syncthreads();
  if (t == 0) {
    float r = 0.f;
    for (int i = 0; i < 16; i++) { soff[i] = r; r += sred[i]; }
  }
  __syncthreads();
  const float base = soff[wv] + (ps - s);
  const float d0 = base + pv.x;
  const float d1 = d0 + pv.y;
  const float d2 = d1 + pv.z;
  const float d3 = d2 + pv.w;
  float4 iv;
  iv.x = 1.f / d0; iv.y = 1.f / d1; iv.z = 1.f / d2; iv.w = 1.f / d3;
  *(float4*)&g_invden[t << 2] = iv;
}

// ---------------- K4b/c/d: chunked column scan of cumsum(p*y)/den ------------
__global__ __launch_bounds__(256) void k_csum()
{
  const int ch = blockIdx.x;
  const int t  = threadIdx.x;
  float ax = 0.f, ay = 0.f, az = 0.f, aw = 0.f;
  for (int r = 0; r < 64; r++) {
    const int row = (ch << 6) + r;
    const float pr = g_p[row];
    const float4 yv = *(const float4*)&g_y[(size_t)row * HID + (t << 2)];
    ax = fmaf(pr, yv.x, ax); ay = fmaf(pr, yv.y, ay);
    az = fmaf(pr, yv.z, az); aw = fmaf(pr, yv.w, aw);
  }
  float4 o; o.x = ax; o.y = ay; o.z = az; o.w = aw;
  *(float4*)&g_csum[(ch << 10) + (t << 2)] = o;
}

__global__ __launch_bounds__(256) void k_cscan()
{
  const int c = blockIdx.x * 256 + threadIdx.x;   // 0..1023
  float run = 0.f;
  for (int ch = 0; ch < 64; ch++) {
    const float v = g_csum[(ch << 10) + c];
    g_csum[(ch << 10) + c] = run;                 // exclusive prefix, in place
    run += v;
  }
}

__global__ __launch_bounds__(256) void k_final(float* __restrict__ out)
{
  const int ch = blockIdx.x;
  const int t  = threadIdx.x;
  float4 run = *(const float4*)&g_csum[(ch << 10) + (t << 2)];
  for (int r = 0; r < 64; r++) {
    const int row = (ch << 6) + r;
    const float pr = g_p[row];
    const float iv = g_invden[row];
    const float4 yv = *(const float4*)&g_y[(size_t)row * HID + (t << 2)];
    run.x = fmaf(pr, yv.x, run.x);
    run.y = fmaf(pr, yv.y, run.y);
    run.z = fmaf(pr, yv.z, run.z);
    run.w = fmaf(pr, yv.w, run.w);
    float4 ov;
    ov.x = run.x * iv; ov.y = run.y * iv; ov.z = run.z * iv; ov.w = run.w * iv;
    *(float4*)&out[(size_t)row * HID + (t << 2)] = ov;
  }
}

// ---------------- host launch --------------------------------------------------
extern "C" void kernel_launch(void* const* d_in, const int* in_sizes, int n_in,
                              void* d_out, int out_size, void* d_ws, size_t ws_size,
                              hipStream_t stream)
{
  (void)in_sizes; (void)n_in; (void)d_ws; (void)ws_size; (void)out_size;

  const float* x        = (const float*)d_in[0];
  const float* bot_Wih  = (const float*)d_in[1];
  const float* bot_Whh  = (const float*)d_in[2];
  const float* bot_bih  = (const float*)d_in[3];
  const float* bot_bhh  = (const float*)d_in[4];
  const float* top_Wih  = (const float*)d_in[5];
  const float* top_Whh  = (const float*)d_in[6];
  const float* top_bih  = (const float*)d_in[7];
  const float* top_bhh  = (const float*)d_in[8];
  const float* hw_w     = (const float*)d_in[9];
  const float* hw_b     = (const float*)d_in[10];
  const float* cw_w     = (const float*)d_in[11];
  const float* cw_b     = (const float*)d_in[12];
  const float* att_bias = (const float*)d_in[13];
  const float* v2s_w    = (const float*)d_in[14];
  const float* v2s_b    = (const float*)d_in[15];
  float* out = (float*)d_out;

  k_init<<<dim3(1), dim3(1), 0, stream>>>();
  k_gemm_xg<<<dim3(32, 32), dim3(256), 0, stream>>>(x, bot_Wih, bot_bih, bot_bhh);
  k_lstm<<<dim3(NWG), dim3(TPB), 0, stream>>>(bot_Whh, top_Wih, top_Whh,
                                              top_bih, top_bhh,
                                              hw_b, cw_w, cw_b, att_bias);
  k_attn_e<<<dim3(256), dim3(256), 0, stream>>>(hw_w, v2s_w, v2s_b);
  k_softmax<<<dim3(1), dim3(1024), 0, stream>>>();
  k_csum<<<dim3(64), dim3(256), 0, stream>>>();
  k_cscan<<<dim3(4), dim3(256), 0, stream>>>();
  k_final<<<dim3(64), dim3(256), 0, stream>>>(out);
}

// Round 2
// 14470.682 us; speedup vs baseline: 5.7482x; 5.7482x over previous
//
#include <hip/hip_runtime.h>
#include <hip/hip_bf16.h>
#include <cstdint>
#include <cstddef>

#define SEQ 4096
#define HID 1024
#define G4  4096
#define NWG 64
#define TPB 512
#define UPL 64

// ---------------- persistent device scratch (avoids ws_size unknowns) ----------
__device__ float    g_xg[(size_t)SEQ * G4];   // 64 MB: input-gate preactivations
__device__ float    g_y [(size_t)SEQ * HID];  // 16 MB: bottom LSTM outputs
__device__ float    g_h [2][HID];             // double-buffered bottom h (atomic)
__device__ float    g_h2[2][HID];             // double-buffered top h    (atomic)
__device__ float    g_upx[(size_t)UPL * HID]; // sampled y rows           (atomic)
__device__ float    g_bias2[HID];             // hw_b + cw_b + att_bias + ctx@cw_w.T
__device__ float    g_e[SEQ];
__device__ float    g_p[SEQ];
__device__ float    g_invden[SEQ];
__device__ float    g_csum[64 * HID];
__device__ unsigned g_bar;

__global__ void k_init() { g_bar = 0u; }

// -------- coherent (cache-bypassing) scalar access via agent-scope atomics -----
__device__ __forceinline__ float atomLoad(float* p) {
  return __hip_atomic_load(p, __ATOMIC_RELAXED, __HIP_MEMORY_SCOPE_AGENT);
}
__device__ __forceinline__ void atomStore(float* p, float v) {
  __hip_atomic_store(p, v, __ATOMIC_RELAXED, __HIP_MEMORY_SCOPE_AGENT);
}

// ---------------- K1: xg = x @ bot_Wih^T + (bih + bhh), fp32 tiled GEMM --------
#define BMT 128
#define BNT 128
#define BKT 32

__global__ __launch_bounds__(256) void k_gemm_xg(const float* __restrict__ A,
                                                 const float* __restrict__ B,
                                                 const float* __restrict__ bias0,
                                                 const float* __restrict__ bias1)
{
  __shared__ float As[BKT][BMT + 4];
  __shared__ float Bs[BKT][BNT + 4];
  const int t  = threadIdx.x;
  const int bn = blockIdx.x;
  const int bm = blockIdx.y;
  const int m0 = (t & 15) * 8;
  const int n0 = (t >> 4) * 8;

  float acc[8][8];
#pragma unroll
  for (int i = 0; i < 8; i++)
#pragma unroll
    for (int j = 0; j < 8; j++) acc[i][j] = 0.f;

  for (int k0 = 0; k0 < 1024; k0 += BKT) {
#pragma unroll
    for (int i = 0; i < 4; i++) {
      const int idx = i * 256 + t;        // 0..1023
      const int m   = idx >> 3;           // 0..127
      const int k4  = (idx & 7) << 2;     // 0..28
      const float4 av = *(const float4*)&A[(size_t)(bm * BMT + m) * 1024 + k0 + k4];
      As[k4 + 0][m] = av.x; As[k4 + 1][m] = av.y; As[k4 + 2][m] = av.z; As[k4 + 3][m] = av.w;
      const float4 bv = *(const float4*)&B[(size_t)(bn * BNT + m) * 1024 + k0 + k4];
      Bs[k4 + 0][m] = bv.x; Bs[k4 + 1][m] = bv.y; Bs[k4 + 2][m] = bv.z; Bs[k4 + 3][m] = bv.w;
    }
    __syncthreads();
#pragma unroll
    for (int k = 0; k < BKT; k++) {
      float a[8], b[8];
      *(float4*)&a[0] = *(const float4*)&As[k][m0];
      *(float4*)&a[4] = *(const float4*)&As[k][m0 + 4];
      *(float4*)&b[0] = *(const float4*)&Bs[k][n0];
      *(float4*)&b[4] = *(const float4*)&Bs[k][n0 + 4];
#pragma unroll
      for (int i = 0; i < 8; i++)
#pragma unroll
        for (int j = 0; j < 8; j++) acc[i][j] = fmaf(a[i], b[j], acc[i][j]);
    }
    __syncthreads();
  }

  float bb[8];
#pragma unroll
  for (int j = 0; j < 8; j++) {
    const int gc = bn * BNT + n0 + j;
    bb[j] = bias0[gc] + bias1[gc];
  }
#pragma unroll
  for (int i = 0; i < 8; i++) {
    const size_t off = (size_t)(bm * BMT + m0 + i) * G4 + bn * BNT + n0;
    float4 v0, v1;
    v0.x = acc[i][0] + bb[0]; v0.y = acc[i][1] + bb[1]; v0.z = acc[i][2] + bb[2]; v0.w = acc[i][3] + bb[3];
    v1.x = acc[i][4] + bb[4]; v1.y = acc[i][5] + bb[5]; v1.z = acc[i][6] + bb[6]; v1.w = acc[i][7] + bb[7];
    *(float4*)&g_xg[off]     = v0;
    *(float4*)&g_xg[off + 4] = v1;
  }
}

// ---------------- K2: persistent LSTM kernel, fence-free atomic protocol -------
// Publisher lanes (t<16) and the barrier-arrival thread (t==0) are in the SAME
// wave: an s_waitcnt vmcnt(0) between the atomic h-stores and the arrival
// fetch_add gives release semantics with NO cache-wide maintenance ops.
__device__ __forceinline__ void grid_sync(unsigned target)
{
  asm volatile("s_waitcnt vmcnt(0)" ::: "memory");  // drain own wave's stores
  __syncthreads();
  if (threadIdx.x == 0) {
    __hip_atomic_fetch_add(&g_bar, 1u, __ATOMIC_RELAXED, __HIP_MEMORY_SCOPE_AGENT);
    while (__hip_atomic_load(&g_bar, __ATOMIC_RELAXED, __HIP_MEMORY_SCOPE_AGENT) < target) { }
  }
  __syncthreads();
  asm volatile("" ::: "memory");                    // no hoisting loads above spin
}

__device__ __forceinline__ float seg_dot32(const float4* __restrict__ wv,
                                           const float* __restrict__ hb, int seg)
{
  float acc = 0.f;
#pragma unroll
  for (int k = 0; k < 32; k++) {
    const float4 hv = *(const float4*)&hb[((k + seg) & 31) << 2]; // rotated: bank-conflict-free
    acc = fmaf(wv[k].x, hv.x, acc);
    acc = fmaf(wv[k].y, hv.y, acc);
    acc = fmaf(wv[k].z, hv.z, acc);
    acc = fmaf(wv[k].w, hv.w, acc);
  }
  return acc;
}

__device__ __forceinline__ void load_wrow(float4* __restrict__ wv,
                                          const float* __restrict__ W, int row, int seg)
{
  const float* wr = W + (size_t)row * HID + (seg << 7);
#pragma unroll
  for (int k = 0; k < 32; k++) wv[k] = *(const float4*)&wr[((k + seg) & 31) << 2];
}

__global__ __launch_bounds__(TPB, 2) void k_lstm(
    const float* __restrict__ bot_Whh,
    const float* __restrict__ top_Wih, const float* __restrict__ top_Whh,
    const float* __restrict__ top_bih, const float* __restrict__ top_bhh,
    const float* __restrict__ hw_b,    const float* __restrict__ cw_w,
    const float* __restrict__ cw_b,    const float* __restrict__ att_bias)
{
  const int w = blockIdx.x;              // 0..63, owns hidden units [16w,16w+16)
  const int t = threadIdx.x;
  const int r_local = t >> 3;            // 0..63 (gate*16 + hu_local)
  const int seg     = t & 7;             // 0..7, 128-wide column segment
  const int row = ((r_local >> 4) << 10) + (w << 4) + (r_local & 15); // gate*1024 + hu

  __shared__ float h_lds[HID];
  __shared__ float gates_lds[64];
  __shared__ float xg2_lds[UPL][64];

  float4 wv[32];                         // 128 fp32 weights, register-resident
  load_wrow(wv, bot_Whh, row, seg);

  float c_state = 0.f;
  unsigned gen = 0;
  const int i0 = t << 1;                 // each thread stages 2 h elements

  // ---- bottom LSTM: 4096 sequential steps ----
  for (int step = 0; step < SEQ; step++) {
    float xval = 0.f;
    if (seg == 0) xval = g_xg[(size_t)step * G4 + row];   // issued early
    if (step == 0) {
      for (int i = t; i < HID; i += TPB) h_lds[i] = 0.f;
    } else {
      float* src = g_h[(step + 1) & 1];
      h_lds[i0]     = atomLoad(&src[i0]);
      h_lds[i0 + 1] = atomLoad(&src[i0 + 1]);
    }
    __syncthreads();
    float acc = seg_dot32(wv, &h_lds[seg << 7], seg);
    acc += __shfl_xor(acc, 4);
    acc += __shfl_xor(acc, 2);
    acc += __shfl_xor(acc, 1);
    if (seg == 0) gates_lds[r_local] = acc + xval;
    __syncthreads();
    if (t < 16) {
      const float gi = gates_lds[t];
      const float gf = gates_lds[16 + t];
      const float gg = gates_lds[32 + t];
      const float go = gates_lds[48 + t];
      const float ii = 1.f / (1.f + expf(-gi));
      const float ff = 1.f / (1.f + expf(-gf));
      c_state = ff * c_state + ii * tanhf(gg);
      const float hh = (1.f / (1.f + expf(-go))) * tanhf(c_state);
      atomStore(&g_h[step & 1][(w << 4) + t], hh);        // coherent publish
      g_y[(size_t)step * HID + (w << 4) + t] = hh;        // for later kernels
      if ((step & 63) == 63)                               // sampled row, in-kernel reuse
        atomStore(&g_upx[(size_t)(step >> 6) * HID + (w << 4) + t], hh);
    }
    ++gen;
    grid_sync(gen * NWG);
  }

  // ---- top-LSTM input projection: xg2[s] = upx[s] @ top_Wih^T + bias ----
  load_wrow(wv, top_Wih, row, seg);
  const float tb = top_bih[row] + top_bhh[row];
  for (int s = 0; s < UPL; s++) {
    __syncthreads();
    {
      float* src = &g_upx[(size_t)s * HID];
      h_lds[i0]     = atomLoad(&src[i0]);
      h_lds[i0 + 1] = atomLoad(&src[i0 + 1]);
    }
    __syncthreads();
    float acc = seg_dot32(wv, &h_lds[seg << 7], seg);
    acc += __shfl_xor(acc, 4);
    acc += __shfl_xor(acc, 2);
    acc += __shfl_xor(acc, 1);
    if (seg == 0) xg2_lds[s][r_local] = acc + tb;
  }

  // ---- top recurrence: 64 steps ----
  load_wrow(wv, top_Whh, row, seg);
  c_state = 0.f;
  for (int s = 0; s < UPL; s++) {
    if (s == 0) {
      __syncthreads();
      for (int i = t; i < HID; i += TPB) h_lds[i] = 0.f;
    } else {
      float* src = g_h2[(s + 1) & 1];
      h_lds[i0]     = atomLoad(&src[i0]);
      h_lds[i0 + 1] = atomLoad(&src[i0 + 1]);
    }
    __syncthreads();
    float acc = seg_dot32(wv, &h_lds[seg << 7], seg);
    acc += __shfl_xor(acc, 4);
    acc += __shfl_xor(acc, 2);
    acc += __shfl_xor(acc, 1);
    if (seg == 0) gates_lds[r_local] = acc + xg2_lds[s][r_local];
    __syncthreads();
    if (t < 16) {
      const float gi = gates_lds[t];
      const float gf = gates_lds[16 + t];
      const float gg = gates_lds[32 + t];
      const float go = gates_lds[48 + t];
      const float ii = 1.f / (1.f + expf(-gi));
      const float ff = 1.f / (1.f + expf(-gf));
      c_state = ff * c_state + ii * tanhf(gg);
      const float hh = (1.f / (1.f + expf(-go))) * tanhf(c_state);
      atomStore(&g_h2[s & 1][(w << 4) + t], hh);
    }
    ++gen;
    grid_sync(gen * NWG);
  }

  // ---- bias2[j] = hw_b + cw_b + att_bias + ctx @ cw_w^T (ctx = g_h2[1]) ----
  __syncthreads();
  {
    float* src = g_h2[1];
    h_lds[i0]     = atomLoad(&src[i0]);
    h_lds[i0 + 1] = atomLoad(&src[i0 + 1]);
  }
  __syncthreads();
  {
    const int jl = t >> 5;            // 0..15
    const int ks = t & 31;            // 0..31
    const int j  = (w << 4) + jl;
    const float* cr = cw_w + (size_t)j * HID + (ks << 5);
    const float* hr = &h_lds[ks << 5];
    float a2 = 0.f;
#pragma unroll
    for (int k = 0; k < 32; k++) a2 = fmaf(cr[k], hr[k], a2);
    a2 += __shfl_xor(a2, 16);
    a2 += __shfl_xor(a2, 8);
    a2 += __shfl_xor(a2, 4);
    a2 += __shfl_xor(a2, 2);
    a2 += __shfl_xor(a2, 1);
    if (ks == 0) g_bias2[j] = a2 + hw_b[j] + cw_b[j] + att_bias[j];
  }
}

// ---------------- K3: e[t] = sum_j v2s_w[j]*tanh(y_t . hw_w[j] + bias2[j]) ----
__global__ __launch_bounds__(256) void k_attn_e(const float* __restrict__ hw_w,
                                                const float* __restrict__ v2s_w,
                                                const float* __restrict__ v2s_b)
{
  __shared__ float ys[16][1028];
  __shared__ float ws[16][1028];
  const int b  = blockIdx.x;          // row block: rows [16b,16b+16)
  const int t  = threadIdx.x;
  const int rg = t >> 6;              // 0..3 (row group of 4)
  const int fg = (t >> 4) & 3;        // 0..3 (feature group of 4)
  const int ks = t & 15;              // 0..15 (k segment of 64)

#pragma unroll
  for (int i = 0; i < 16; i++) {
    const int idx = i * 256 + t;
    const int r   = idx >> 8;
    const int c4  = (idx & 255) << 2;
    *(float4*)&ys[r][c4] = *(const float4*)&g_y[(size_t)((b << 4) + r) * HID + c4];
  }

  float e_acc[4] = {0.f, 0.f, 0.f, 0.f};
  for (int f0 = 0; f0 < HID; f0 += 16) {
    __syncthreads();
#pragma unroll
    for (int i = 0; i < 16; i++) {
      const int idx = i * 256 + t;
      const int r   = idx >> 8;
      const int c4  = (idx & 255) << 2;
      *(float4*)&ws[r][c4] = *(const float4*)&hw_w[(size_t)(f0 + r) * HID + c4];
    }
    __syncthreads();

    float acc[4][4];
#pragma unroll
    for (int u = 0; u < 4; u++)
#pragma unroll
      for (int v = 0; v < 4; v++) acc[u][v] = 0.f;

#pragma unroll
    for (int m = 0; m < 16; m++) {
      const int k4 = (ks << 6) + (((m + ks) & 15) << 2);  // rotated k within segment
      float4 av[4], bv[4];
#pragma unroll
      for (int u = 0; u < 4; u++) av[u] = *(const float4*)&ys[(rg << 2) + u][k4];
#pragma unroll
      for (int v = 0; v < 4; v++) bv[v] = *(const float4*)&ws[(fg << 2) + v][k4];
#pragma unroll
      for (int u = 0; u < 4; u++)
#pragma unroll
        for (int v = 0; v < 4; v++) {
          acc[u][v] = fmaf(av[u].x, bv[v].x, acc[u][v]);
          acc[u][v] = fmaf(av[u].y, bv[v].y, acc[u][v]);
          acc[u][v] = fmaf(av[u].z, bv[v].z, acc[u][v]);
          acc[u][v] = fmaf(av[u].w, bv[v].w, acc[u][v]);
        }
    }
#pragma unroll
    for (int u = 0; u < 4; u++)
#pragma unroll
      for (int v = 0; v < 4; v++) {
        float s2 = acc[u][v];
        s2 += __shfl_xor(s2, 8);
        s2 += __shfl_xor(s2, 4);
        s2 += __shfl_xor(s2, 2);
        s2 += __shfl_xor(s2, 1);
        acc[u][v] = s2;
      }
    if (ks == 0) {
#pragma unroll
      for (int v = 0; v < 4; v++) {
        const int j = f0 + (fg << 2) + v;
        const float bias = g_bias2[j];
        const float vw   = v2s_w[j];
#pragma unroll
        for (int u = 0; u < 4; u++)
          e_acc[u] += vw * tanhf(acc[u][v] + bias);
      }
    }
  }
#pragma unroll
  for (int u = 0; u < 4; u++) {
    float s2 = e_acc[u];
    s2 += __shfl_xor(s2, 16);
    s2 += __shfl_xor(s2, 32);
    if (fg == 0 && ks == 0) g_e[(b << 4) + (rg << 2) + u] = s2 + v2s_b[0];
  }
}

// ---------------- K4a: p = exp(e - max e); invden = 1/cumsum(p) --------------
__global__ __launch_bounds__(1024) void k_softmax()
{
  const int t  = threadIdx.x;
  const int ln = t & 63;
  const int wv = t >> 6;
  __shared__ float sred[16];
  __shared__ float soff[16];
  __shared__ float sM;

  const float4 ev = *(const float4*)&g_e[t << 2];
  float mx = fmaxf(fmaxf(ev.x, ev.y), fmaxf(ev.z, ev.w));
#pragma unroll
  for (int d = 32; d >= 1; d >>= 1) mx = fmaxf(mx, __shfl_xor(mx, d));
  if (ln == 0) sred[wv] = mx;
  __syncthreads();
  if (t == 0) {
    float m2 = sred[0];
    for (int i = 1; i < 16; i++) m2 = fmaxf(m2, sred[i]);
    sM = m2;
  }
  __syncthreads();
  const float M = sM;
  float4 pv;
  pv.x = expf(ev.x - M); pv.y = expf(ev.y - M); pv.z = expf(ev.z - M); pv.w = expf(ev.w - M);
  *(float4*)&g_p[t << 2] = pv;

  const float s = pv.x + pv.y + pv.z + pv.w;
  float ps = s;
#pragma unroll
  for (int d = 1; d < 64; d <<= 1) {
    const float v = __shfl_up(ps, d);
    if (ln >= d) ps += v;
  }
  __syncthreads();
  if (ln == 63) sred[wv] = ps;
  __syncthreads();
  if (t == 0) {
    float r = 0.f;
    for (int i = 0; i < 16; i++) { soff[i] = r; r += sred[i]; }
  }
  __syncthreads();
  const float base = soff[wv] + (ps - s);
  const float d0 = base + pv.x;
  const float d1 = d0 + pv.y;
  const float d2 = d1 + pv.z;
  const float d3 = d2 + pv.w;
  float4 iv;
  iv.x = 1.f / d0; iv.y = 1.f / d1; iv.z = 1.f / d2; iv.w = 1.f / d3;
  *(float4*)&g_invden[t << 2] = iv;
}

// ---------------- K4b/c/d: chunked column scan of cumsum(p*y)/den ------------
__global__ __launch_bounds__(256) void k_csum()
{
  const int ch = blockIdx.x;
  const int t  = threadIdx.x;
  float ax = 0.f, ay = 0.f, az = 0.f, aw = 0.f;
  for (int r = 0; r < 64; r++) {
    const int row = (ch << 6) + r;
    const float pr = g_p[row];
    const float4 yv = *(const float4*)&g_y[(size_t)row * HID + (t << 2)];
    ax = fmaf(pr, yv.x, ax); ay = fmaf(pr, yv.y, ay);
    az = fmaf(pr, yv.z, az); aw = fmaf(pr, yv.w, aw);
  }
  float4 o; o.x = ax; o.y = ay; o.z = az; o.w = aw;
  *(float4*)&g_csum[(ch << 10) + (t << 2)] = o;
}

__global__ __launch_bounds__(256) void k_cscan()
{
  const int c = blockIdx.x * 256 + threadIdx.x;   // 0..1023
  float run = 0.f;
  for (int ch = 0; ch < 64; ch++) {
    const float v = g_csum[(ch << 10) + c];
    g_csum[(ch << 10) + c] = run;                 // exclusive prefix, in place
    run += v;
  }
}

__global__ __launch_bounds__(256) void k_final(float* __restrict__ out)
{
  const int ch = blockIdx.x;
  const int t  = threadIdx.x;
  float4 run = *(const float4*)&g_csum[(ch << 10) + (t << 2)];
  for (int r = 0; r < 64; r++) {
    const int row = (ch << 6) + r;
    const float pr = g_p[row];
    const float iv = g_invden[row];
    const float4 yv = *(const float4*)&g_y[(size_t)row * HID + (t << 2)];
    run.x = fmaf(pr, yv.x, run.x);
    run.y = fmaf(pr, yv.y, run.y);
    run.z = fmaf(pr, yv.z, run.z);
    run.w = fmaf(pr, yv.w, run.w);
    float4 ov;
    ov.x = run.x * iv; ov.y = run.y * iv; ov.z = run.z * iv; ov.w = run.w * iv;
    *(float4*)&out[(size_t)row * HID + (t << 2)] = ov;
  }
}

// ---------------- host launch --------------------------------------------------
extern "C" void kernel_launch(void* const* d_in, const int* in_sizes, int n_in,
                              void* d_out, int out_size, void* d_ws, size_t ws_size,
                              hipStream_t stream)
{
  (void)in_sizes; (void)n_in; (void)d_ws; (void)ws_size; (void)out_size;

  const float* x        = (const float*)d_in[0];
  const float* bot_Wih  = (const float*)d_in[1];
  const float* bot_Whh  = (const float*)d_in[2];
  const float* bot_bih  = (const float*)d_in[3];
  const float* bot_bhh  = (const float*)d_in[4];
  const float* top_Wih  = (const float*)d_in[5];
  const float* top_Whh  = (const float*)d_in[6];
  const float* top_bih  = (const float*)d_in[7];
  const float* top_bhh  = (const float*)d_in[8];
  const float* hw_w     = (const float*)d_in[9];
  const float* hw_b     = (const float*)d_in[10];
  const float* cw_w     = (const float*)d_in[11];
  const float* cw_b     = (const float*)d_in[12];
  const float* att_bias = (const float*)d_in[13];
  const float* v2s_w    = (const float*)d_in[14];
  const float* v2s_b    = (const float*)d_in[15];
  float* out = (float*)d_out;

  k_init<<<dim3(1), dim3(1), 0, stream>>>();
  k_gemm_xg<<<dim3(32, 32), dim3(256), 0, stream>>>(x, bot_Wih, bot_bih, bot_bhh);
  k_lstm<<<dim3(NWG), dim3(TPB), 0, stream>>>(bot_Whh, top_Wih, top_Whh,
                                              top_bih, top_bhh,
                                              hw_b, cw_w, cw_b, att_bias);
  k_attn_e<<<dim3(256), dim3(256), 0, stream>>>(hw_w, v2s_w, v2s_b);
  k_softmax<<<dim3(1), dim3(1024), 0, stream>>>();
  k_csum<<<dim3(64), dim3(256), 0, stream>>>();
  k_cscan<<<dim3(4), dim3(256), 0, stream>>>();
  k_final<<<dim3(64), dim3(256), 0, stream>>>(out);
}